// Round 1
// baseline (180.944 us; speedup 1.0000x reference)
//
#include <hip/hip_runtime.h>

#define BQ 32
#define TQ 128
#define U1Q 65
#define UMAXQ 64
#define DQ 512
#define NEGQ (-1e30f)

// logaddexp for finite (possibly hugely negative) fp32 values
__device__ __forceinline__ float logaddf(float a, float b) {
    float mx = fmaxf(a, b);
    float mn = fminf(a, b);
    // mn-mx <= 0; __expf underflows cleanly to 0 for very negative args
    return mx + __logf(1.0f + __expf(mn - mx));
}

// Phase 1: per (b,t,u) cell, logsumexp over D=512, emit lp_blank & masked lp_emit.
// One wave (64 lanes) per cell; lane i holds elements [4i..4i+3] and [256+4i..256+4i+3].
__global__ __launch_bounds__(256) void lse_k(const float* __restrict__ logits,
                                             const int* __restrict__ targets,
                                             const int* __restrict__ tlen,
                                             float* __restrict__ lpb,
                                             float* __restrict__ lpe) {
    int gid  = blockIdx.x * blockDim.x + threadIdx.x;
    int cell = gid >> 6;
    int lane = threadIdx.x & 63;
    if (cell >= BQ * TQ * U1Q) return;

    const float* row = logits + (size_t)cell * DQ;
    float4 v0 = *(const float4*)(row + lane * 4);
    float4 v1 = *(const float4*)(row + 256 + lane * 4);

    float m = fmaxf(fmaxf(fmaxf(v0.x, v0.y), fmaxf(v0.z, v0.w)),
                    fmaxf(fmaxf(v1.x, v1.y), fmaxf(v1.z, v1.w)));
#pragma unroll
    for (int d = 32; d >= 1; d >>= 1) m = fmaxf(m, __shfl_xor(m, d, 64));

    float s = __expf(v0.x - m) + __expf(v0.y - m) + __expf(v0.z - m) + __expf(v0.w - m)
            + __expf(v1.x - m) + __expf(v1.y - m) + __expf(v1.z - m) + __expf(v1.w - m);
#pragma unroll
    for (int d = 32; d >= 1; d >>= 1) s += __shfl_xor(s, d, 64);

    float lse = m + __logf(s);

    int u = cell % U1Q;
    int b = cell / (TQ * U1Q);

    // blank = element 511 = lane 63's v1.w
    float blankv = __shfl(v1.w, 63, 64);

    int tl  = tlen[b];
    int tgt = (u < UMAXQ) ? targets[b * UMAXQ + u] : 0;  // padded target (masked anyway)

    // locate target element among this lane's 8 values
    float ev = 0.0f;
#pragma unroll
    for (int j = 0; j < 4; ++j) {
        if (lane * 4 + j == tgt)       ev = (&v0.x)[j];
        if (256 + lane * 4 + j == tgt) ev = (&v1.x)[j];
    }
    int srclane = (tgt & 255) >> 2;
    float emitv = __shfl(ev, srclane, 64);

    if (lane == 0) {
        lpb[cell] = blankv - lse;
        lpe[cell] = (u < tl) ? (emitv - lse) : NEGQ;
    }
}

// Phase 2: one wave per batch. Log-semiring affine Kogge-Stone scan over u.
// Recurrence: a[u] = logaddexp(skip[u], a[u-1] + e[u-1]); affine map x->logadd(x+M, C);
// compose(first A, then B): M = A.M + B.M ; C = logadd(A.C + B.M, B.C).
__global__ __launch_bounds__(64) void dp_k(const float* __restrict__ lpb,
                                           const float* __restrict__ lpe,
                                           const int* __restrict__ llen,
                                           const int* __restrict__ tlen,
                                           float* __restrict__ out) {
    int b    = blockIdx.x;
    int lane = threadIdx.x;  // 0..63 ; lane l holds u = l+1

    const float* LPB = lpb + (size_t)b * TQ * U1Q;
    const float* LPE = lpe + (size_t)b * TQ * U1Q;

    int tf = llen[b] - 1;   // final row index (63..127)
    int uf = tlen[b];       // final u index (32..64)

    // row0: prev[u=l+1] = inclusive prefix sum of e0[0..l]; prev0 = 0
    float p = LPE[lane];
#pragma unroll
    for (int d = 1; d <= 32; d <<= 1) {
        float o = __shfl_up(p, d, 64);
        if (lane >= d) p += o;
    }
    float prev  = p;
    float prev0 = 0.0f;

    // software-pipelined row loads
    float bl0 = LPB[0];                      // lp_blank[t-1][0]
    float blv = LPB[lane + 1];               // lp_blank[t-1][lane+1]
    float emv = LPE[(size_t)U1Q + lane];     // lp_emit[t][lane]

    for (int t = 1; t <= tf; ++t) {
        float cbl0 = bl0, cblv = blv, cemv = emv;
        if (t < tf) {
            bl0 = LPB[(size_t)t * U1Q];
            blv = LPB[(size_t)t * U1Q + lane + 1];
            emv = LPE[(size_t)(t + 1) * U1Q + lane];
        }

        float skip0 = prev0 + cbl0;
        float C = prev + cblv;   // c[u=lane+1] = skip[lane+1]
        float M = cemv;          // m[u=lane+1] = e_t[lane]

#pragma unroll
        for (int d = 1; d <= 32; d <<= 1) {
            float Mo = __shfl_up(M, d, 64);
            float Co = __shfl_up(C, d, 64);
            if (lane >= d) {
                C = logaddf(Co + M, C);
                M = M + Mo;
            }
        }

        float a = logaddf(skip0 + M, C);  // a[u=lane+1]
        prev  = a;
        prev0 = skip0;
    }

    float alpha_f = (uf == 0) ? prev0 : __shfl(prev, uf - 1, 64);
    float lpb_f   = LPB[(size_t)tf * U1Q + uf];
    if (lane == 0) out[b] = -(alpha_f + lpb_f);
}

extern "C" void kernel_launch(void* const* d_in, const int* in_sizes, int n_in,
                              void* d_out, int out_size, void* d_ws, size_t ws_size,
                              hipStream_t stream) {
    const float* logits  = (const float*)d_in[0];
    const int*   llen    = (const int*)d_in[1];
    const int*   tlen    = (const int*)d_in[2];
    const int*   targets = (const int*)d_in[3];
    float*       out     = (float*)d_out;

    float* lpb = (float*)d_ws;
    float* lpe = lpb + (size_t)BQ * TQ * U1Q;

    int cells  = BQ * TQ * U1Q;                 // 266240
    int blocks = (cells * 64 + 255) / 256;      // 4 waves/block

    lse_k<<<blocks, 256, 0, stream>>>(logits, targets, tlen, lpb, lpe);
    dp_k<<<BQ, 64, 0, stream>>>(lpb, lpe, llen, tlen, out);
}

// Round 3
// 141.191 us; speedup vs baseline: 1.2816x; 1.2816x over previous
//
#include <hip/hip_runtime.h>

#define BQ 32
#define TQ 128
#define U1Q 65
#define UMAXQ 64
#define DQ 512
#define NCELLS (BQ * TQ * U1Q)
#define NEGQ (-1e30f)
#define L2E 1.4426950408889634f
#define LN2F 0.6931471805599453f

// log2-domain logaddexp: log2(2^x + 2^y). exp2f/log2f are native on CDNA.
__device__ __forceinline__ float logadd2(float x, float y) {
    float mx = fmaxf(x, y);
    float d  = fminf(x, y) - mx;            // <= 0; exp2 underflows cleanly
    return mx + log2f(1.0f + exp2f(d));
}

// Phase 1: 4 rows per wave, 16 lanes per row. Each lane holds 32 elements
// (8 float4s) of its row -> single memory pass, in-register max & sum-exp2.
// Emits log2-domain lp_blank and masked lp_emit.
__global__ __launch_bounds__(256) void lse_k(const float* __restrict__ logits,
                                             const int* __restrict__ targets,
                                             const int* __restrict__ tlen,
                                             float* __restrict__ lpb,
                                             float* __restrict__ lpe) {
    int wid  = (blockIdx.x * 256 + threadIdx.x) >> 6;
    int lane = threadIdx.x & 63;
    int g = lane >> 4;          // row within wave
    int i = lane & 15;          // sublane within row
    int r = wid * 4 + g;        // global cell index (grid sized exactly)

    const float4* rp = (const float4*)(logits + (size_t)r * DQ) + i;
    // lane i holds elements {4i + 64k + j : k=0..7, j=0..3}
    float4 v0 = rp[0],  v1 = rp[16], v2 = rp[32], v3 = rp[48],
           v4 = rp[64], v5 = rp[80], v6 = rp[96], v7 = rp[112];

#define MAX4(v) fmaxf(fmaxf((v).x, (v).y), fmaxf((v).z, (v).w))
    float m = fmaxf(fmaxf(fmaxf(MAX4(v0), MAX4(v1)), fmaxf(MAX4(v2), MAX4(v3))),
                    fmaxf(fmaxf(MAX4(v4), MAX4(v5)), fmaxf(MAX4(v6), MAX4(v7))));
#pragma unroll
    for (int d = 1; d <= 8; d <<= 1) m = fmaxf(m, __shfl_xor(m, d, 64));

    float ml = m * L2E;
#define SUM4(v) (exp2f(fmaf((v).x, L2E, -ml)) + exp2f(fmaf((v).y, L2E, -ml)) + \
                 exp2f(fmaf((v).z, L2E, -ml)) + exp2f(fmaf((v).w, L2E, -ml)))
    float s = ((SUM4(v0) + SUM4(v1)) + (SUM4(v2) + SUM4(v3))) +
              ((SUM4(v4) + SUM4(v5)) + (SUM4(v6) + SUM4(v7)));
#pragma unroll
    for (int d = 1; d <= 8; d <<= 1) s += __shfl_xor(s, d, 64);

    float l2s = log2f(s);

    int b = r / (TQ * U1Q);
    int u = (r - b * TQ * U1Q) % U1Q;

    // blank = element 511 = lane i==15's v7.w
    if (i == 15) lpb[r] = fmaf(v7.w, L2E, -ml) - l2s;

    int tl  = tlen[b];
    int tgt = targets[b * UMAXQ + (u < UMAXQ ? u : UMAXQ - 1)];
    int itgt = (tgt >> 2) & 15;
    if (i == itgt) {
        int ktgt = tgt >> 6, jt = tgt & 3;
        float4 c = v0;
        if (ktgt == 1) c = v1;
        if (ktgt == 2) c = v2;
        if (ktgt == 3) c = v3;
        if (ktgt == 4) c = v4;
        if (ktgt == 5) c = v5;
        if (ktgt == 6) c = v6;
        if (ktgt == 7) c = v7;
        float val = (jt == 0) ? c.x : ((jt == 1) ? c.y : ((jt == 2) ? c.z : c.w));
        lpe[r] = (u < tl) ? (fmaf(val, L2E, -ml) - l2s) : NEGQ;
    }
}

// Phase 2: anti-diagonal wavefront DP, one wave per batch.
// lane u holds alpha[t=k-u][u] on diagonal k; u=64 tracked wave-uniformly.
__global__ __launch_bounds__(64) void dp_k(const float* __restrict__ lpb,
                                           const float* __restrict__ lpe,
                                           const int* __restrict__ llen,
                                           const int* __restrict__ tlen,
                                           float* __restrict__ out) {
    int b    = blockIdx.x;
    int lane = threadIdx.x;
    const float* LPB = lpb + (size_t)b * TQ * U1Q;
    const float* LPE = lpe + (size_t)b * TQ * U1Q;

    int tf = llen[b] - 1;
    int uf = tlen[b];
    int kmax = tf + uf;

    float a   = (lane == 0) ? 0.0f : NEGQ;
    float a64 = NEGQ;
    int um1 = (lane > 0) ? lane - 1 : 0;

    // clamped (always in-bounds) diagonal loads; garbage values are masked
    auto LB = [&](int k) { int t = k - lane - 1; t = t < 0 ? 0 : (t > TQ - 1 ? TQ - 1 : t);
                           return LPB[t * U1Q + lane]; };
    auto LE = [&](int k) { int t = k - lane;     t = t < 0 ? 0 : (t > TQ - 1 ? TQ - 1 : t);
                           return LPE[t * U1Q + um1]; };
    auto LB6 = [&](int k) { int t = k - 65; t = t < 0 ? 0 : (t > TQ - 1 ? TQ - 1 : t);
                            return LPB[t * U1Q + 64]; };
    auto LE6 = [&](int k) { int t = k - 64; t = t < 0 ? 0 : (t > TQ - 1 ? TQ - 1 : t);
                            return LPE[t * U1Q + 63]; };

#define STEP(kk, lbv, lev, lb6v, le6v) do {                                  \
    int k_ = (kk); int t = k_ - lane;                                        \
    float A   = (t >= 1) ? (a + (lbv)) : NEGQ;                               \
    float ash = __shfl_up(a, 1, 64);                                         \
    float Bv  = (lane >= 1 && t >= 0) ? (ash + (lev)) : NEGQ;                \
    float a63 = __shfl(a, 63, 64);                                           \
    float anew = logadd2(A, Bv);                                             \
    int t64 = k_ - 64;                                                       \
    float A64 = (t64 >= 1) ? (a64 + (lb6v)) : NEGQ;                          \
    float B64 = (t64 >= 0) ? (a63 + (le6v)) : NEGQ;                          \
    a64 = (t64 >= 0) ? logadd2(A64, B64) : NEGQ;                             \
    a = anew;                                                                \
} while (0)

    // 4-deep software-pipelined prefetch (all addresses clamped in-bounds)
    float lbA = LB(1), leA = LE(1), lb6A = LB6(1), le6A = LE6(1);
    float lbB = LB(2), leB = LE(2), lb6B = LB6(2), le6B = LE6(2);
    float lbC = LB(3), leC = LE(3), lb6C = LB6(3), le6C = LE6(3);
    float lbD = LB(4), leD = LE(4), lb6D = LB6(4), le6D = LE6(4);

    int k = 1;
    for (; k + 3 <= kmax; k += 4) {
        STEP(k,     lbA, leA, lb6A, le6A); lbA = LB(k + 4); leA = LE(k + 4); lb6A = LB6(k + 4); le6A = LE6(k + 4);
        STEP(k + 1, lbB, leB, lb6B, le6B); lbB = LB(k + 5); leB = LE(k + 5); lb6B = LB6(k + 5); le6B = LE6(k + 5);
        STEP(k + 2, lbC, leC, lb6C, le6C); lbC = LB(k + 6); leC = LE(k + 6); lb6C = LB6(k + 6); le6C = LE6(k + 6);
        STEP(k + 3, lbD, leD, lb6D, le6D); lbD = LB(k + 7); leD = LE(k + 7); lb6D = LB6(k + 7); le6D = LE6(k + 7);
    }
    if (k <= kmax) { STEP(k, lbA, leA, lb6A, le6A); k++; }
    if (k <= kmax) { STEP(k, lbB, leB, lb6B, le6B); k++; }
    if (k <= kmax) { STEP(k, lbC, leC, lb6C, le6C); k++; }

    float alpha_f = (uf >= 64) ? a64 : __shfl(a, uf, 64);
    if (lane == 0) out[b] = -(alpha_f + LPB[tf * U1Q + uf]) * LN2F;
}

extern "C" void kernel_launch(void* const* d_in, const int* in_sizes, int n_in,
                              void* d_out, int out_size, void* d_ws, size_t ws_size,
                              hipStream_t stream) {
    const float* logits  = (const float*)d_in[0];
    const int*   llen    = (const int*)d_in[1];
    const int*   tlen    = (const int*)d_in[2];
    const int*   targets = (const int*)d_in[3];
    float*       out     = (float*)d_out;

    float* lpb = (float*)d_ws;
    float* lpe = lpb + (size_t)NCELLS;

    int blocks = NCELLS / 16;   // 4 waves/block x 4 rows/wave = 16 rows/block, exact
    lse_k<<<blocks, 256, 0, stream>>>(logits, targets, tlen, lpb, lpe);
    dp_k<<<BQ, 64, 0, stream>>>(lpb, lpe, llen, tlen, out);
}

// Round 4
// 125.839 us; speedup vs baseline: 1.4379x; 1.1220x over previous
//
#include <hip/hip_runtime.h>

#define BQ 32
#define TQ 128
#define U1Q 65
#define UMAXQ 64
#define DQ 512
#define SLAB (TQ * U1Q)          // 8320 floats per array per batch
#define NCELLS (BQ * SLAB)
#define NEGQ (-1e30f)
#define L2E 1.4426950408889634f
#define LN2F 0.6931471805599453f

typedef float f4 __attribute__((ext_vector_type(4)));

// log2-domain logaddexp: log2(2^x + 2^y). exp2f/log2f are native on CDNA.
__device__ __forceinline__ float logadd2(float x, float y) {
    float mx = fmaxf(x, y);
    float d  = fminf(x, y) - mx;            // <= 0; exp2 underflows cleanly
    return mx + log2f(1.0f + exp2f(d));
}

// Phase 1: 4 rows per wave, 16 lanes per row; nontemporal streaming loads.
// ws layout: per batch b, ws[b*2*SLAB + q] = lp_blank, ws[b*2*SLAB + SLAB + q] = lp_emit
// (q = t*U1Q + u), both in log2 domain.
__global__ __launch_bounds__(512) void lse_k(const float* __restrict__ logits,
                                             const int* __restrict__ targets,
                                             const int* __restrict__ tlen,
                                             float* __restrict__ ws) {
    int wid  = (blockIdx.x * 512 + threadIdx.x) >> 6;
    int lane = threadIdx.x & 63;
    int g = lane >> 4;          // row within wave
    int i = lane & 15;          // sublane within row
    int r = wid * 4 + g;        // global cell index (grid sized exactly)

    const f4* rp = (const f4*)(logits + (size_t)r * DQ) + i;
    // lane i holds elements {4i + 64k + j : k=0..7, j=0..3}
    f4 v0 = __builtin_nontemporal_load(rp);
    f4 v1 = __builtin_nontemporal_load(rp + 16);
    f4 v2 = __builtin_nontemporal_load(rp + 32);
    f4 v3 = __builtin_nontemporal_load(rp + 48);
    f4 v4 = __builtin_nontemporal_load(rp + 64);
    f4 v5 = __builtin_nontemporal_load(rp + 80);
    f4 v6 = __builtin_nontemporal_load(rp + 96);
    f4 v7 = __builtin_nontemporal_load(rp + 112);

#define MAX4(v) fmaxf(fmaxf((v).x, (v).y), fmaxf((v).z, (v).w))
    float m = fmaxf(fmaxf(fmaxf(MAX4(v0), MAX4(v1)), fmaxf(MAX4(v2), MAX4(v3))),
                    fmaxf(fmaxf(MAX4(v4), MAX4(v5)), fmaxf(MAX4(v6), MAX4(v7))));
#pragma unroll
    for (int d = 1; d <= 8; d <<= 1) m = fmaxf(m, __shfl_xor(m, d, 64));

    float ml = m * L2E;
#define SUM4(v) (exp2f(fmaf((v).x, L2E, -ml)) + exp2f(fmaf((v).y, L2E, -ml)) + \
                 exp2f(fmaf((v).z, L2E, -ml)) + exp2f(fmaf((v).w, L2E, -ml)))
    float s = ((SUM4(v0) + SUM4(v1)) + (SUM4(v2) + SUM4(v3))) +
              ((SUM4(v4) + SUM4(v5)) + (SUM4(v6) + SUM4(v7)));
#pragma unroll
    for (int d = 1; d <= 8; d <<= 1) s += __shfl_xor(s, d, 64);

    float l2s = log2f(s);

    int b = r / SLAB;
    int q = r - b * SLAB;
    int u = q % U1Q;
    float* wb = ws + (size_t)b * 2 * SLAB;

    // blank = element 511 = lane i==15's v7.w
    if (i == 15) wb[q] = fmaf(v7.w, L2E, -ml) - l2s;

    int tl  = tlen[b];
    int tgt = targets[b * UMAXQ + (u < UMAXQ ? u : UMAXQ - 1)];
    int itgt = (tgt >> 2) & 15;
    if (i == itgt) {
        int ktgt = tgt >> 6, jt = tgt & 3;
        f4 c = v0;
        if (ktgt == 1) c = v1;
        if (ktgt == 2) c = v2;
        if (ktgt == 3) c = v3;
        if (ktgt == 4) c = v4;
        if (ktgt == 5) c = v5;
        if (ktgt == 6) c = v6;
        if (ktgt == 7) c = v7;
        float val = (jt == 0) ? c.x : ((jt == 1) ? c.y : ((jt == 2) ? c.z : c.w));
        wb[SLAB + q] = (u < tl) ? (fmaf(val, L2E, -ml) - l2s) : NEGQ;
    }
}

// Phase 2: per batch, stage the 66.5 KB slab into LDS with 4 waves, then
// wave 0 runs the anti-diagonal wavefront DP out of LDS (4-deep prefetch).
__global__ __launch_bounds__(256) void dp_k(const float* __restrict__ ws,
                                            const int* __restrict__ llen,
                                            const int* __restrict__ tlen,
                                            float* __restrict__ out) {
    __shared__ float S[2 * SLAB];
    int b   = blockIdx.x;
    int tid = threadIdx.x;

    const f4* src = (const f4*)(ws + (size_t)b * 2 * SLAB);
    f4* dst = (f4*)S;
    for (int idx = tid; idx < (2 * SLAB) / 4; idx += 256) dst[idx] = src[idx];
    __syncthreads();
    if (tid >= 64) return;

    int lane = tid;
    const float* SB = S;
    const float* SE = S + SLAB;

    int tf = llen[b] - 1;
    int uf = tlen[b];
    int kmax = tf + uf;

    float a   = (lane == 0) ? 0.0f : NEGQ;
    float a64 = NEGQ;
    int um1 = (lane > 0) ? lane - 1 : 0;

    // clamped (always in-bounds) diagonal reads from LDS; garbage is masked
    auto LB = [&](int k) { int t = k - lane - 1; t = t < 0 ? 0 : (t > TQ - 1 ? TQ - 1 : t);
                           return SB[t * U1Q + lane]; };
    auto LE = [&](int k) { int t = k - lane;     t = t < 0 ? 0 : (t > TQ - 1 ? TQ - 1 : t);
                           return SE[t * U1Q + um1]; };
    auto LB6 = [&](int k) { int t = k - 65; t = t < 0 ? 0 : (t > TQ - 1 ? TQ - 1 : t);
                            return SB[t * U1Q + 64]; };
    auto LE6 = [&](int k) { int t = k - 64; t = t < 0 ? 0 : (t > TQ - 1 ? TQ - 1 : t);
                            return SE[t * U1Q + 63]; };

#define STEP(kk, lbv, lev, lb6v, le6v) do {                                  \
    int k_ = (kk); int t = k_ - lane;                                        \
    float A   = (t >= 1) ? (a + (lbv)) : NEGQ;                               \
    float ash = __shfl_up(a, 1, 64);                                         \
    float Bv  = (lane >= 1 && t >= 0) ? (ash + (lev)) : NEGQ;                \
    float a63 = __shfl(a, 63, 64);                                           \
    float anew = logadd2(A, Bv);                                             \
    int t64 = k_ - 64;                                                       \
    float A64 = (t64 >= 1) ? (a64 + (lb6v)) : NEGQ;                          \
    float B64 = (t64 >= 0) ? (a63 + (le6v)) : NEGQ;                          \
    a64 = (t64 >= 0) ? logadd2(A64, B64) : NEGQ;                             \
    a = anew;                                                                \
} while (0)

    // 4-deep software-pipelined prefetch (all addresses clamped in-bounds)
    float lbA = LB(1), leA = LE(1), lb6A = LB6(1), le6A = LE6(1);
    float lbB = LB(2), leB = LE(2), lb6B = LB6(2), le6B = LE6(2);
    float lbC = LB(3), leC = LE(3), lb6C = LB6(3), le6C = LE6(3);
    float lbD = LB(4), leD = LE(4), lb6D = LB6(4), le6D = LE6(4);

    int k = 1;
    for (; k + 3 <= kmax; k += 4) {
        STEP(k,     lbA, leA, lb6A, le6A); lbA = LB(k + 4); leA = LE(k + 4); lb6A = LB6(k + 4); le6A = LE6(k + 4);
        STEP(k + 1, lbB, leB, lb6B, le6B); lbB = LB(k + 5); leB = LE(k + 5); lb6B = LB6(k + 5); le6B = LE6(k + 5);
        STEP(k + 2, lbC, leC, lb6C, le6C); lbC = LB(k + 6); leC = LE(k + 6); lb6C = LB6(k + 6); le6C = LE6(k + 6);
        STEP(k + 3, lbD, leD, lb6D, le6D); lbD = LB(k + 7); leD = LE(k + 7); lb6D = LB6(k + 7); le6D = LE6(k + 7);
    }
    if (k <= kmax) { STEP(k, lbA, leA, lb6A, le6A); k++; }
    if (k <= kmax) { STEP(k, lbB, leB, lb6B, le6B); k++; }
    if (k <= kmax) { STEP(k, lbC, leC, lb6C, le6C); k++; }

    float alpha_f = (uf >= 64) ? a64 : __shfl(a, uf, 64);
    if (lane == 0) out[b] = -(alpha_f + SB[tf * U1Q + uf]) * LN2F;
}

extern "C" void kernel_launch(void* const* d_in, const int* in_sizes, int n_in,
                              void* d_out, int out_size, void* d_ws, size_t ws_size,
                              hipStream_t stream) {
    const float* logits  = (const float*)d_in[0];
    const int*   llen    = (const int*)d_in[1];
    const int*   tlen    = (const int*)d_in[2];
    const int*   targets = (const int*)d_in[3];
    float*       out     = (float*)d_out;
    float*       ws      = (float*)d_ws;

    int blocks = NCELLS / 32;   // 8 waves/block x 4 rows/wave = 32 rows/block, exact
    lse_k<<<blocks, 512, 0, stream>>>(logits, targets, tlen, ws);
    dp_k<<<BQ, 256, 0, stream>>>(ws, llen, tlen, out);
}

// Round 5
// 88.142 us; speedup vs baseline: 2.0529x; 1.4277x over previous
//
#include <hip/hip_runtime.h>

#define BQ 32
#define TQ 128
#define U1Q 65
#define UMAXQ 64
#define DQ 512
#define SLAB (TQ * U1Q)          // 8320 floats per array per batch
#define NCELLS (BQ * SLAB)
#define NEGQ (-1e30f)
#define L2E 1.4426950408889634f
#define LN2F 0.6931471805599453f

typedef float f4 __attribute__((ext_vector_type(4)));

// log2-domain logaddexp: log2(2^x + 2^y). exp2f/log2f are native on CDNA.
__device__ __forceinline__ float logadd2(float x, float y) {
    float mx = fmaxf(x, y);
    float d  = fminf(x, y) - mx;            // <= 0; exp2 underflows cleanly
    return mx + log2f(1.0f + exp2f(d));
}

// Phase 1: 4 rows per wave, 16 lanes per row; nontemporal streaming loads.
// Rows with t >= llen[b] or u > tlen[b] are never consumed by the DP -> skip
// them before loading (cuts HBM read to ~57%).
// ws layout: per batch b, ws[b*2*SLAB + q] = lp_blank, ws[b*2*SLAB + SLAB + q]
// = lp_emit (q = t*U1Q + u), both log2-domain.
__global__ __launch_bounds__(512) void lse_k(const float* __restrict__ logits,
                                             const int* __restrict__ targets,
                                             const int* __restrict__ llen,
                                             const int* __restrict__ tlen,
                                             float* __restrict__ ws) {
    int wid  = (blockIdx.x * 512 + threadIdx.x) >> 6;
    int lane = threadIdx.x & 63;
    int g = lane >> 4;          // row within wave
    int i = lane & 15;          // sublane within row
    int r = wid * 4 + g;        // global cell index (grid sized exactly)

    int b = r / SLAB;
    int q = r - b * SLAB;
    int t = q / U1Q;
    int u = q - t * U1Q;
    int tl = tlen[b];
    if (t >= llen[b] || u > tl) return;   // uniform across the 16-lane group

    const f4* rp = (const f4*)(logits + (size_t)r * DQ) + i;
    // lane i holds elements {4i + 64k + j : k=0..7, j=0..3}
    f4 v0 = __builtin_nontemporal_load(rp);
    f4 v1 = __builtin_nontemporal_load(rp + 16);
    f4 v2 = __builtin_nontemporal_load(rp + 32);
    f4 v3 = __builtin_nontemporal_load(rp + 48);
    f4 v4 = __builtin_nontemporal_load(rp + 64);
    f4 v5 = __builtin_nontemporal_load(rp + 80);
    f4 v6 = __builtin_nontemporal_load(rp + 96);
    f4 v7 = __builtin_nontemporal_load(rp + 112);

#define MAX4(v) fmaxf(fmaxf((v).x, (v).y), fmaxf((v).z, (v).w))
    float m = fmaxf(fmaxf(fmaxf(MAX4(v0), MAX4(v1)), fmaxf(MAX4(v2), MAX4(v3))),
                    fmaxf(fmaxf(MAX4(v4), MAX4(v5)), fmaxf(MAX4(v6), MAX4(v7))));
#pragma unroll
    for (int d = 1; d <= 8; d <<= 1) m = fmaxf(m, __shfl_xor(m, d, 64));

    float ml = m * L2E;
#define SUM4(v) (exp2f(fmaf((v).x, L2E, -ml)) + exp2f(fmaf((v).y, L2E, -ml)) + \
                 exp2f(fmaf((v).z, L2E, -ml)) + exp2f(fmaf((v).w, L2E, -ml)))
    float s = ((SUM4(v0) + SUM4(v1)) + (SUM4(v2) + SUM4(v3))) +
              ((SUM4(v4) + SUM4(v5)) + (SUM4(v6) + SUM4(v7)));
#pragma unroll
    for (int d = 1; d <= 8; d <<= 1) s += __shfl_xor(s, d, 64);

    float l2s = log2f(s);
    float* wb = ws + (size_t)b * 2 * SLAB;

    // blank = element 511 = lane i==15's v7.w
    if (i == 15) wb[q] = fmaf(v7.w, L2E, -ml) - l2s;

    int tgt = targets[b * UMAXQ + (u < UMAXQ ? u : UMAXQ - 1)];
    int itgt = (tgt >> 2) & 15;
    if (i == itgt) {
        int ktgt = tgt >> 6, jt = tgt & 3;
        f4 c = v0;
        if (ktgt == 1) c = v1;
        if (ktgt == 2) c = v2;
        if (ktgt == 3) c = v3;
        if (ktgt == 4) c = v4;
        if (ktgt == 5) c = v5;
        if (ktgt == 6) c = v6;
        if (ktgt == 7) c = v7;
        float val = (jt == 0) ? c.x : ((jt == 1) ? c.y : ((jt == 2) ? c.z : c.w));
        wb[SLAB + q] = (u < tl) ? (fmaf(val, L2E, -ml) - l2s) : NEGQ;
    }
}

// Phase 2: per batch, stage rows t<=tf of both slabs into LDS (8 waves), then
// wave 0 runs the anti-diagonal wavefront DP out of LDS (4-deep prefetch).
__global__ __launch_bounds__(512) void dp_k(const float* __restrict__ ws,
                                            const int* __restrict__ llen,
                                            const int* __restrict__ tlen,
                                            float* __restrict__ out) {
    __shared__ float S[2 * SLAB];
    int b   = blockIdx.x;
    int tid = threadIdx.x;

    int tf = llen[b] - 1;
    int uf = tlen[b];

    const f4* srcB = (const f4*)(ws + (size_t)b * 2 * SLAB);
    const f4* srcE = srcB + SLAB / 4;
    f4* dstB = (f4*)S;
    f4* dstE = (f4*)(S + SLAB);
    int nb4 = ((tf + 1) * U1Q + 3) >> 2;      // f4s covering rows 0..tf
    for (int idx = tid; idx < nb4; idx += 512) {
        dstB[idx] = srcB[idx];
        dstE[idx] = srcE[idx];
    }
    __syncthreads();
    if (tid >= 64) return;

    int lane = tid;
    const float* SB = S;
    const float* SE = S + SLAB;

    int kmax = tf + uf;

    float a   = (lane == 0) ? 0.0f : NEGQ;
    float a64 = NEGQ;
    int um1 = (lane > 0) ? lane - 1 : 0;

    // clamped (always in-bounds) diagonal reads from LDS; garbage is masked
    // or confined to lanes/diagonals that never reach the output (see notes).
    auto LB = [&](int k) { int t = k - lane - 1; t = t < 0 ? 0 : (t > TQ - 1 ? TQ - 1 : t);
                           return SB[t * U1Q + lane]; };
    auto LE = [&](int k) { int t = k - lane;     t = t < 0 ? 0 : (t > TQ - 1 ? TQ - 1 : t);
                           return SE[t * U1Q + um1]; };
    auto LB6 = [&](int k) { int t = k - 65; t = t < 0 ? 0 : (t > TQ - 1 ? TQ - 1 : t);
                            return SB[t * U1Q + 64]; };
    auto LE6 = [&](int k) { int t = k - 64; t = t < 0 ? 0 : (t > TQ - 1 ? TQ - 1 : t);
                            return SE[t * U1Q + 63]; };

#define STEP(kk, lbv, lev, lb6v, le6v) do {                                  \
    int k_ = (kk); int t = k_ - lane;                                        \
    float A   = (t >= 1) ? (a + (lbv)) : NEGQ;                               \
    float ash = __shfl_up(a, 1, 64);                                         \
    float Bv  = (lane >= 1 && t >= 0) ? (ash + (lev)) : NEGQ;                \
    float a63 = __shfl(a, 63, 64);                                           \
    float anew = logadd2(A, Bv);                                             \
    int t64 = k_ - 64;                                                       \
    float A64 = (t64 >= 1) ? (a64 + (lb6v)) : NEGQ;                          \
    float B64 = (t64 >= 0) ? (a63 + (le6v)) : NEGQ;                          \
    a64 = (t64 >= 0) ? logadd2(A64, B64) : NEGQ;                             \
    a = anew;                                                                \
} while (0)

    // 4-deep software-pipelined prefetch (all addresses clamped in-bounds)
    float lbA = LB(1), leA = LE(1), lb6A = LB6(1), le6A = LE6(1);
    float lbB = LB(2), leB = LE(2), lb6B = LB6(2), le6B = LE6(2);
    float lbC = LB(3), leC = LE(3), lb6C = LB6(3), le6C = LE6(3);
    float lbD = LB(4), leD = LE(4), lb6D = LB6(4), le6D = LE6(4);

    int k = 1;
    for (; k + 3 <= kmax; k += 4) {
        STEP(k,     lbA, leA, lb6A, le6A); lbA = LB(k + 4); leA = LE(k + 4); lb6A = LB6(k + 4); le6A = LE6(k + 4);
        STEP(k + 1, lbB, leB, lb6B, le6B); lbB = LB(k + 5); leB = LE(k + 5); lb6B = LB6(k + 5); le6B = LE6(k + 5);
        STEP(k + 2, lbC, leC, lb6C, le6C); lbC = LB(k + 6); leC = LE(k + 6); lb6C = LB6(k + 6); le6C = LE6(k + 6);
        STEP(k + 3, lbD, leD, lb6D, le6D); lbD = LB(k + 7); leD = LE(k + 7); lb6D = LB6(k + 7); le6D = LE6(k + 7);
    }
    if (k <= kmax) { STEP(k, lbA, leA, lb6A, le6A); k++; }
    if (k <= kmax) { STEP(k, lbB, leB, lb6B, le6B); k++; }
    if (k <= kmax) { STEP(k, lbC, leC, lb6C, le6C); k++; }

    float alpha_f = (uf >= 64) ? a64 : __shfl(a, uf, 64);
    if (lane == 0) out[b] = -(alpha_f + SB[tf * U1Q + uf]) * LN2F;
}

extern "C" void kernel_launch(void* const* d_in, const int* in_sizes, int n_in,
                              void* d_out, int out_size, void* d_ws, size_t ws_size,
                              hipStream_t stream) {
    const float* logits  = (const float*)d_in[0];
    const int*   llen    = (const int*)d_in[1];
    const int*   tlen    = (const int*)d_in[2];
    const int*   targets = (const int*)d_in[3];
    float*       out     = (float*)d_out;
    float*       ws      = (float*)d_ws;

    int blocks = NCELLS / 32;   // 8 waves/block x 4 rows/wave = 32 rows/block, exact
    lse_k<<<blocks, 512, 0, stream>>>(logits, targets, llen, tlen, ws);
    dp_k<<<BQ, 512, 0, stream>>>(ws, llen, tlen, out);
}